// Round 1
// baseline (399.177 us; speedup 1.0000x reference)
//
#include <hip/hip_runtime.h>

// SOM vector-quantizer fused kernel for MI355X (gfx950).
// Outputs (flat in d_out): [0] loss scalar, [1 .. 8388608] quantized_st
// in [B,C,D,H,W] layout, [8388609 ..] one-hot encodings [N,256].
//
// N = 262144 voxels, EMB_D = 32, K = 256 (16x16 SOM grid).
//
// R3 -> R4:
//  * distance scan no longer reads W rows from LDS. The row index k is
//    wave-uniform, so rows are read straight from global memory with a
//    uniform index -> compiler promotes to s_load_dwordx16 (SMEM pipe,
//    SGPR operands). v_fmac_f32 takes one SGPR source, so operand
//    delivery costs zero LDS/VALU issue slots. R3's 2048 ds_read_b128
//    per wave (the per-CU LDS pipe was the serializing resource, ~150us)
//    drop to 512 s_loads on the otherwise-idle scalar pipe.
//  * wl/wsql LDS staging kept ONLY for the divergent bidx gather phases
//    (quantized row + 4 SOM neighbors), which genuinely need per-lane
//    addressing. Everything else (enc store ordering, slot atomics,
//    fmaf ordering for absmax 0.0) identical to R3.

#define SOM_K      256
#define EMB_D      32
#define WPAD       36             // LDS row stride (floats): 16B-aligned rows
#define N_VOX      262144
#define SPATIAL    32768          // 32*32*32 per batch
#define OUT_ELEMS  8388608        // 8*32*32768
#define COMMIT_DEN 8388608.0f
#define NSLOT      256            // loss accumulator slots (64B apart)

// ---------------------------------------------------------------------------
// prep: zero the slot accumulators (ws is poisoned to 0xAA every launch).
// Layout: ws[slot*16 + {0,1,2}] = {commit, som, count} partials.
// ---------------------------------------------------------------------------
__global__ __launch_bounds__(256) void som_prep_kernel(float* __restrict__ ws) {
  float4* p = (float4*)ws;               // 256 slots * 16 floats = 1024 float4
  int t = threadIdx.x;
#pragma unroll
  for (int i = 0; i < 4; ++i) p[i * 256 + t] = make_float4(0.f, 0.f, 0.f, 0.f);
}

// ---------------------------------------------------------------------------
// main fused kernel: 1024 blocks x 256 threads, one thread per voxel.
// ---------------------------------------------------------------------------
__global__ __launch_bounds__(256) void som_main_kernel(
    const float* __restrict__ x,     // [8,32,32,32,32]
    const float* __restrict__ w,     // [256,32]
    float* __restrict__ slots,       // ws: NSLOT x 16 floats
    float* __restrict__ out,         // d_out+1, [8,32,32768]
    float* __restrict__ enc) {       // d_out+1+OUT_ELEMS, [N,256]
  __shared__ __align__(16) float wl[SOM_K * WPAD];
  __shared__ float wsql[SOM_K];      // ||W_k||^2

  const int t = threadIdx.x;
  const float* __restrict__ wa =
      (const float*)__builtin_assume_aligned(w, 16);

  // Issue the voxel loads FIRST so they overlap the LDS staging below.
  const int n    = blockIdx.x * 256 + t;
  const int base = (n >> 15) * (EMB_D * SPATIAL) + (n & (SPATIAL - 1));
  float xv[EMB_D];
#pragma unroll
  for (int c = 0; c < EMB_D; ++c) xv[c] = x[base + c * SPATIAL];

  // Stage W -> LDS (coalesced read, padded scatter write). Needed only for
  // the divergent gather phases after the scan.
#pragma unroll
  for (int i = 0; i < 32; ++i) {
    int e = i * 256 + t;             // 0..8191
    int r = e >> 5, c = e & 31;
    wl[r * WPAD + c] = w[e];
  }
  // ||W_t||^2, same sequential-fmaf order as the reference-matched R1..R3.
  {
    float s = 0.0f;
#pragma unroll
    for (int c = 0; c < EMB_D; ++c) {
      float v = w[t * EMB_D + c];
      s = fmaf(v, v, s);
    }
    wsql[t] = s;
  }
  __syncthreads();

  float xsq = 0.0f;
#pragma unroll
  for (int c = 0; c < EMB_D; ++c) xsq = fmaf(xv[c], xv[c], xsq);

  // Distance scan over all 256 codebook rows. k is wave-uniform, so wr[j]
  // is a uniform address -> s_load (SMEM) into SGPRs; the fma chain reads
  // one SGPR + one VGPR per op. Zero LDS traffic in this loop except the
  // wsql[k] b32 broadcast. Exact sequential fmaf order kept (absmax 0.0).
  float best = 3.402823466e38f;
  int   bidx = 0;
#pragma unroll 2
  for (int k = 0; k < SOM_K; ++k) {
    const float* __restrict__ wr = wa + (k << 5);
    float dot = 0.0f;
#pragma unroll
    for (int j = 0; j < EMB_D; ++j) dot = fmaf(wr[j], xv[j], dot);
    float d = (xsq + wsql[k]) - 2.0f * dot;   // same rounding order as ref
    if (d < best) { best = d; bidx = k; }
  }

  // One-hot encodings FIRST (only needs bidx): start draining the 268 MB
  // write stream while the LDS gather phases below run. Each wave broadcasts
  // its own 64 BMU indices via v_readlane; stores are coalesced 256B dwords
  // (enc region starts at float offset 8388609 == 1 mod 4 -> dword only).
  {
    const int lane = t & 63, wave = t >> 6;
    float* ep = enc + (size_t)(blockIdx.x * 256 + wave * 64) * SOM_K + lane;
    const int c1 = lane + 64, c2 = lane + 128, c3 = lane + 192;
    for (int row = 0; row < 64; ++row) {
      const int src = __builtin_amdgcn_readlane(bidx, row);  // wave-uniform
      ep[0]   = (lane == src) ? 1.0f : 0.0f;
      ep[64]  = (c1   == src) ? 1.0f : 0.0f;
      ep[128] = (c2   == src) ? 1.0f : 0.0f;
      ep[192] = (c3   == src) ? 1.0f : 0.0f;
      ep += SOM_K;
    }
  }

  // Quantized output + commitment-loss partial (gather row bidx from LDS).
  float commit = 0.0f;
  {
    const float4* qrow = (const float4*)(wl + bidx * WPAD);
#pragma unroll
    for (int j = 0; j < 8; ++j) {
      float4 q = qrow[j];
      float qq[4] = { q.x, q.y, q.z, q.w };
#pragma unroll
      for (int u = 0; u < 4; ++u) {
        int c = 4 * j + u;
        out[base + c * SPATIAL] = qq[u];     // coalesced dword store
        float df = qq[u] - xv[c];
        commit = fmaf(df, df, commit);
      }
    }
  }

  // SOM loss: dist to BMU + its up/down/left/right grid neighbors.
  float som = best;
  float cnt = 1.0f;
  {
    const int h  = bidx >> 4;
    const int wc = bidx & 15;
    const int   cand[4]  = { bidx - 16, bidx + 16, bidx - 1, bidx + 1 };
    const float valid[4] = { h > 0 ? 1.f : 0.f,  h < 15 ? 1.f : 0.f,
                             wc > 0 ? 1.f : 0.f, wc < 15 ? 1.f : 0.f };
#pragma unroll
    for (int j = 0; j < 4; ++j) {
      int nk = valid[j] != 0.0f ? cand[j] : bidx;   // clamp (masked anyway)
      const float4* nrow = (const float4*)(wl + nk * WPAD);
      float dot = 0.0f;
#pragma unroll
      for (int jj = 0; jj < 8; ++jj) {
        float4 q = nrow[jj];
        dot = fmaf(q.x, xv[4 * jj + 0], dot);
        dot = fmaf(q.y, xv[4 * jj + 1], dot);
        dot = fmaf(q.z, xv[4 * jj + 2], dot);
        dot = fmaf(q.w, xv[4 * jj + 3], dot);
      }
      float d = (xsq + wsql[nk]) - 2.0f * dot;
      som = fmaf(valid[j], d, som);
      cnt += valid[j];
    }
  }

  // Wave reduction -> 3 atomics per wave into this block's slot (slots are
  // 64B apart; 16 waves/slot -> negligible contention, parallel L2 banks).
  for (int off = 32; off > 0; off >>= 1) {
    commit += __shfl_down(commit, off, 64);
    som    += __shfl_down(som,    off, 64);
    cnt    += __shfl_down(cnt,    off, 64);
  }
  if ((t & 63) == 0) {
    float* sp = slots + (size_t)(blockIdx.x & (NSLOT - 1)) * 16;
    atomicAdd(sp + 0, commit);
    atomicAdd(sp + 1, som);
    atomicAdd(sp + 2, cnt);
  }
}

// ---------------------------------------------------------------------------
// final: reduce the 256 slots with one wave, then
// loss = ALPHA * mean(commit) + BETA * som_sum / total_neighbors
// ---------------------------------------------------------------------------
__global__ __launch_bounds__(64) void som_final_kernel(
    const float* __restrict__ slots, float* __restrict__ loss) {
  const int t = threadIdx.x;           // one wave
  float commit = 0.f, som = 0.f, cnt = 0.f;
#pragma unroll
  for (int i = 0; i < 4; ++i) {
    const float* sp = slots + (size_t)(i * 64 + t) * 16;
    commit += sp[0]; som += sp[1]; cnt += sp[2];
  }
  for (int off = 32; off > 0; off >>= 1) {
    commit += __shfl_down(commit, off, 64);
    som    += __shfl_down(som,    off, 64);
    cnt    += __shfl_down(cnt,    off, 64);
  }
  if (t == 0) loss[0] = 6.0f * (commit / COMMIT_DEN) + som / cnt;
}

extern "C" void kernel_launch(void* const* d_in, const int* in_sizes, int n_in,
                              void* d_out, int out_size, void* d_ws, size_t ws_size,
                              hipStream_t stream) {
  const float* x = (const float*)d_in[0];   // [8,32,32,32,32]
  const float* w = (const float*)d_in[1];   // [256,32]
  float* ws  = (float*)d_ws;                // NSLOT x 16 float slots
  float* o   = (float*)d_out;               // [0] loss, then out, then enc

  som_prep_kernel<<<1, 256, 0, stream>>>(ws);
  som_main_kernel<<<N_VOX / 256, 256, 0, stream>>>(
      x, w, ws, o + 1, o + 1 + OUT_ELEMS);
  som_final_kernel<<<1, 64, 0, stream>>>(ws, o);
}

// Round 2
// 382.950 us; speedup vs baseline: 1.0424x; 1.0424x over previous
//
#include <hip/hip_runtime.h>

// SOM vector-quantizer fused kernel for MI355X (gfx950).
// Outputs (flat in d_out): [0] loss scalar, [1 .. 8388608] quantized_st
// in [B,C,D,H,W] layout, [8388609 ..] one-hot encodings [N,256].
//
// N = 262144 voxels, EMB_D = 32, K = 256 (16x16 SOM grid).
//
// R4 -> R5:
//  * distance-scan W reads go through the CONSTANT address space (4),
//    cast via integer round-trip (composable_kernel's
//    cast_pointer_to_constant_address_space idiom). AS4 loads cannot
//    alias our out/enc stores and are scalarized for the uniform row
//    index k -> guaranteed s_load_dwordx8/x16 into SGPRs on the scalar
//    pipe. R4's generic-pointer version left the compiler free to emit
//    per-lane global_load_dwordx4 (alias-conservative), which just moved
//    R3's 2048-inst/wave LDS operand flood onto the L1/VMEM pipe --
//    explaining the near-null 413->399 delta. With SGPR delivery the
//    scan is pure VALU issue (~32 us/SIMD at 4 waves) overlapped with
//    the 302 MB store drain.
//  * Everything else (LDS gather phases, enc store ordering, slot
//    atomics, exact fmaf order for absmax 0.0) identical to R4.

#define SOM_K      256
#define EMB_D      32
#define WPAD       36             // LDS row stride (floats): 16B-aligned rows
#define N_VOX      262144
#define SPATIAL    32768          // 32*32*32 per batch
#define OUT_ELEMS  8388608        // 8*32*32768
#define COMMIT_DEN 8388608.0f
#define NSLOT      256            // loss accumulator slots (64B apart)

#define CONST_AS __attribute__((address_space(4)))

// ---------------------------------------------------------------------------
// prep: zero the slot accumulators (ws is poisoned to 0xAA every launch).
// Layout: ws[slot*16 + {0,1,2}] = {commit, som, count} partials.
// ---------------------------------------------------------------------------
__global__ __launch_bounds__(256) void som_prep_kernel(float* __restrict__ ws) {
  float4* p = (float4*)ws;               // 256 slots * 16 floats = 1024 float4
  int t = threadIdx.x;
#pragma unroll
  for (int i = 0; i < 4; ++i) p[i * 256 + t] = make_float4(0.f, 0.f, 0.f, 0.f);
}

// ---------------------------------------------------------------------------
// main fused kernel: 1024 blocks x 256 threads, one thread per voxel.
// ---------------------------------------------------------------------------
__global__ __launch_bounds__(256) void som_main_kernel(
    const float* __restrict__ x,     // [8,32,32,32,32]
    const float* __restrict__ w,     // [256,32]
    float* __restrict__ slots,       // ws: NSLOT x 16 floats
    float* __restrict__ out,         // d_out+1, [8,32,32768]
    float* __restrict__ enc) {       // d_out+1+OUT_ELEMS, [N,256]
  __shared__ __align__(16) float wl[SOM_K * WPAD];
  __shared__ float wsql[SOM_K];      // ||W_k||^2

  const int t = threadIdx.x;
  // Constant-address-space view of the codebook: s_load + no-alias by
  // construction (CK cast_pointer_to_constant_address_space idiom).
  const CONST_AS float* wc = (const CONST_AS float*)(unsigned long long)w;

  // Issue the voxel loads FIRST so they overlap the LDS staging below.
  const int n    = blockIdx.x * 256 + t;
  const int base = (n >> 15) * (EMB_D * SPATIAL) + (n & (SPATIAL - 1));
  float xv[EMB_D];
#pragma unroll
  for (int c = 0; c < EMB_D; ++c) xv[c] = x[base + c * SPATIAL];

  // Stage W -> LDS (coalesced read, padded scatter write). Needed only for
  // the divergent gather phases after the scan.
#pragma unroll
  for (int i = 0; i < 32; ++i) {
    int e = i * 256 + t;             // 0..8191
    int r = e >> 5, c = e & 31;
    wl[r * WPAD + c] = w[e];
  }
  // ||W_t||^2, same sequential-fmaf order as the reference-matched R1..R4.
  {
    float s = 0.0f;
#pragma unroll
    for (int c = 0; c < EMB_D; ++c) {
      float v = w[t * EMB_D + c];
      s = fmaf(v, v, s);
    }
    wsql[t] = s;
  }
  __syncthreads();

  float xsq = 0.0f;
#pragma unroll
  for (int c = 0; c < EMB_D; ++c) xsq = fmaf(xv[c], xv[c], xsq);

  // Distance scan over all 256 codebook rows. k is wave-uniform and wc is
  // constant-AS -> rows arrive as s_load_dwordx16 in SGPRs; each fmaf is
  // v_fmac_f32 vdst, sgpr, vgpr. Zero vector-memory traffic in this loop
  // except the wsql[k] b32 broadcast. Exact sequential fmaf order kept
  // (absmax 0.0).
  float best = 3.402823466e38f;
  int   bidx = 0;
#pragma unroll 2
  for (int k = 0; k < SOM_K; ++k) {
    const CONST_AS float* wr = wc + (k << 5);
    float dot = 0.0f;
#pragma unroll
    for (int j = 0; j < EMB_D; ++j) dot = fmaf(wr[j], xv[j], dot);
    float d = (xsq + wsql[k]) - 2.0f * dot;   // same rounding order as ref
    if (d < best) { best = d; bidx = k; }
  }

  // One-hot encodings FIRST (only needs bidx): start draining the 268 MB
  // write stream while the LDS gather phases below run. Each wave broadcasts
  // its own 64 BMU indices via v_readlane; stores are coalesced 256B dwords
  // (enc region starts at float offset 8388609 == 1 mod 4 -> dword only).
  {
    const int lane = t & 63, wave = t >> 6;
    float* ep = enc + (size_t)(blockIdx.x * 256 + wave * 64) * SOM_K + lane;
    const int c1 = lane + 64, c2 = lane + 128, c3 = lane + 192;
    for (int row = 0; row < 64; ++row) {
      const int src = __builtin_amdgcn_readlane(bidx, row);  // wave-uniform
      ep[0]   = (lane == src) ? 1.0f : 0.0f;
      ep[64]  = (c1   == src) ? 1.0f : 0.0f;
      ep[128] = (c2   == src) ? 1.0f : 0.0f;
      ep[192] = (c3   == src) ? 1.0f : 0.0f;
      ep += SOM_K;
    }
  }

  // Quantized output + commitment-loss partial (gather row bidx from LDS).
  float commit = 0.0f;
  {
    const float4* qrow = (const float4*)(wl + bidx * WPAD);
#pragma unroll
    for (int j = 0; j < 8; ++j) {
      float4 q = qrow[j];
      float qq[4] = { q.x, q.y, q.z, q.w };
#pragma unroll
      for (int u = 0; u < 4; ++u) {
        int c = 4 * j + u;
        out[base + c * SPATIAL] = qq[u];     // coalesced dword store
        float df = qq[u] - xv[c];
        commit = fmaf(df, df, commit);
      }
    }
  }

  // SOM loss: dist to BMU + its up/down/left/right grid neighbors.
  float som = best;
  float cnt = 1.0f;
  {
    const int h  = bidx >> 4;
    const int wc2 = bidx & 15;
    const int   cand[4]  = { bidx - 16, bidx + 16, bidx - 1, bidx + 1 };
    const float valid[4] = { h > 0 ? 1.f : 0.f,  h < 15 ? 1.f : 0.f,
                             wc2 > 0 ? 1.f : 0.f, wc2 < 15 ? 1.f : 0.f };
#pragma unroll
    for (int j = 0; j < 4; ++j) {
      int nk = valid[j] != 0.0f ? cand[j] : bidx;   // clamp (masked anyway)
      const float4* nrow = (const float4*)(wl + nk * WPAD);
      float dot = 0.0f;
#pragma unroll
      for (int jj = 0; jj < 8; ++jj) {
        float4 q = nrow[jj];
        dot = fmaf(q.x, xv[4 * jj + 0], dot);
        dot = fmaf(q.y, xv[4 * jj + 1], dot);
        dot = fmaf(q.z, xv[4 * jj + 2], dot);
        dot = fmaf(q.w, xv[4 * jj + 3], dot);
      }
      float d = (xsq + wsql[nk]) - 2.0f * dot;
      som = fmaf(valid[j], d, som);
      cnt += valid[j];
    }
  }

  // Wave reduction -> 3 atomics per wave into this block's slot (slots are
  // 64B apart; 16 waves/slot -> negligible contention, parallel L2 banks).
  for (int off = 32; off > 0; off >>= 1) {
    commit += __shfl_down(commit, off, 64);
    som    += __shfl_down(som,    off, 64);
    cnt    += __shfl_down(cnt,    off, 64);
  }
  if ((t & 63) == 0) {
    float* sp = slots + (size_t)(blockIdx.x & (NSLOT - 1)) * 16;
    atomicAdd(sp + 0, commit);
    atomicAdd(sp + 1, som);
    atomicAdd(sp + 2, cnt);
  }
}

// ---------------------------------------------------------------------------
// final: reduce the 256 slots with one wave, then
// loss = ALPHA * mean(commit) + BETA * som_sum / total_neighbors
// ---------------------------------------------------------------------------
__global__ __launch_bounds__(64) void som_final_kernel(
    const float* __restrict__ slots, float* __restrict__ loss) {
  const int t = threadIdx.x;           // one wave
  float commit = 0.f, som = 0.f, cnt = 0.f;
#pragma unroll
  for (int i = 0; i < 4; ++i) {
    const float* sp = slots + (size_t)(i * 64 + t) * 16;
    commit += sp[0]; som += sp[1]; cnt += sp[2];
  }
  for (int off = 32; off > 0; off >>= 1) {
    commit += __shfl_down(commit, off, 64);
    som    += __shfl_down(som,    off, 64);
    cnt    += __shfl_down(cnt,    off, 64);
  }
  if (t == 0) loss[0] = 6.0f * (commit / COMMIT_DEN) + som / cnt;
}

extern "C" void kernel_launch(void* const* d_in, const int* in_sizes, int n_in,
                              void* d_out, int out_size, void* d_ws, size_t ws_size,
                              hipStream_t stream) {
  const float* x = (const float*)d_in[0];   // [8,32,32,32,32]
  const float* w = (const float*)d_in[1];   // [256,32]
  float* ws  = (float*)d_ws;                // NSLOT x 16 float slots
  float* o   = (float*)d_out;               // [0] loss, then out, then enc

  som_prep_kernel<<<1, 256, 0, stream>>>(ws);
  som_main_kernel<<<N_VOX / 256, 256, 0, stream>>>(
      x, w, ws, o + 1, o + 1 + OUT_ELEMS);
  som_final_kernel<<<1, 64, 0, stream>>>(ws, o);
}